// Round 1
// 229.204 us; speedup vs baseline: 1.0870x; 1.0870x over previous
//
#include <hip/hip_runtime.h>
#include <hip/hip_bf16.h>

// GCN layer. Algebra: A2[n] = A1[n].*x[n], so only A1 (+cnt) is edge-accumulated.
//   out[n] = LeakyReLU(A1@W1^T + (A1.*x[n])@W2^T + c*(b1+b2), 0.2)
//
// Pipeline (5 kernels):
//   1. prep_init: bf16 node table + gcur[b] = b*BCAP (region bases)
//   2. part_scatter (1024 thr, 4096 edges/block): LDS bin-sort by bucket
//      (dst>>7, NB=782 bins, one bin per thread for the scan), ONE global
//      atomicAdd per non-empty bucket reserves a CONTIGUOUS run, runs dumped
//      coalesced. ~300K atomics, sequential record lines -> no write-amp.
//   3. bucket_sort (782 blocks x 512 thr): per 128-node bucket, hist loc,
//      scan, direct global scatter into epk2 (18 KB window, L2-coalesced).
//      Emits per-node offsets2[b*129+loc].
//   4. accumulate: ONE WAVE PER NODE. R9: 8 lanes x dwordx4 per edge
//      (8 edges in flight per wave iter, 2-way unrolled -> 2 independent
//      16B/lane gathers outstanding). R8 was half-wave x dword (latency-
//      bound: 35% HBM, 34% VALU, VGPR=12 -> no pipelining headroom).
//   5. node_gemm: 32 rows/block, fused A2=A1.*xd, stride-65 LDS transpose.
//
// Record: uint2{ src, (dst<<15) | q15(norm) }  (dst<131072 fits 17 bits)
// ws (4B units): cnt[N] | gcur[NB] | offsets2[NB*129] | epk[NB*BCAP*2] |
//                epk2[NB*BCAP*2] | xbf[N*32]   (epk 16B-aligned for dwordx4)
// bf16 packing: word w of node n = bf16(x[w+32])<<16 | bf16(x[w])

#define CHUNK 4096
#define NBMAX 1024
#define BCAP  2304   // per-128-node-bucket capacity: mean 2046, sigma 45 -> +5.7σ

__device__ __forceinline__ unsigned int f2bf(float f) {
    unsigned int u = __float_as_uint(f);
    u += 0x7fffu + ((u >> 16) & 1u);
    return u >> 16;
}

__global__ __launch_bounds__(256) void prep_init_kernel(
    const float* __restrict__ srcEmb, const float* __restrict__ dstEmb,
    unsigned int* __restrict__ xbf, int* __restrict__ gcur,
    int Ntot, int n_src, int NB)
{
    int i = blockIdx.x * 256 + threadIdx.x;
    if (i < NB) gcur[i] = i * BCAP;
    if (i >= Ntot * 32) return;
    int n = i >> 5, w = i & 31;
    const float* row = (n < n_src) ? srcEmb + (size_t)n * 64
                                   : dstEmb + (size_t)(n - n_src) * 64;
    xbf[i] = (f2bf(row[w + 32]) << 16) | f2bf(row[w]);
}

// 1024 threads, 4096 edges/block (4 per thread, held in registers).
__global__ __launch_bounds__(1024) void part_scatter_kernel(
    const int* __restrict__ es, const int* __restrict__ ed,
    const float* __restrict__ norm, int* __restrict__ gcur,
    uint2* __restrict__ epk, int E, int NB)
{
    __shared__ int   bcnt[NBMAX];    // counts -> local cursors
    __shared__ int   lstart[NBMAX];  // local run starts
    __shared__ int   gbase[NBMAX];   // reserved global run bases
    __shared__ int   sc[NBMAX];
    __shared__ uint2 sorted[CHUNK];  // 32 KB

    int t  = threadIdx.x;
    int e0 = blockIdx.x * CHUNK;

    bcnt[t] = 0;
    __syncthreads();

    // pass 1: histogram by bucket; dst held in registers for pass 2
    int dreg[4];
    #pragma unroll
    for (int k = 0; k < 4; ++k) {
        int e = e0 + t + k * 1024;
        dreg[k] = (e < E) ? ed[e] : -1;
        if (dreg[k] >= 0) atomicAdd(&bcnt[dreg[k] >> 7], 1);
    }
    __syncthreads();

    // full-block scan over NBMAX bins (one bin per thread) + run reservation
    int c = (t < NB) ? bcnt[t] : 0;
    sc[t] = c;
    __syncthreads();
    for (int off = 1; off < NBMAX; off <<= 1) {
        int x = 0;
        if (t >= off) x = sc[t - off];
        __syncthreads();
        if (t >= off) sc[t] += x;
        __syncthreads();
    }
    int ex = sc[t] - c;
    lstart[t] = ex;
    bcnt[t]   = ex;                 // becomes local cursor
    if (c > 0) gbase[t] = atomicAdd(&gcur[t], c);
    __syncthreads();

    // pass 2: place records into LDS sorted-by-bucket order
    #pragma unroll
    for (int k = 0; k < 4; ++k) {
        int e = e0 + t + k * 1024;
        if (dreg[k] >= 0) {
            unsigned int q = (unsigned int)(norm[e] * 32767.f + 0.5f);
            if (q > 32767u) q = 32767u;
            int lp = atomicAdd(&bcnt[dreg[k] >> 7], 1);
            uint2 r; r.x = (unsigned int)es[e];
            r.y = ((unsigned int)dreg[k] << 15) | q;
            sorted[lp] = r;
        }
    }
    __syncthreads();

    // pass 3: coalesced run dump
    int total = E - e0; if (total > CHUNK) total = CHUNK;
    for (int i = t; i < total; i += 1024) {
        uint2 r = sorted[i];
        int b = (int)(r.y >> 22);                 // dst >> 7
        int gpos = gbase[b] + (i - lstart[b]);
        if (gpos < (b + 1) * BCAP)                // overflow guard
            epk[gpos] = r;
    }
}

// One 512-thread block per 128-node bucket: hist by loc, scan, direct global
// scatter into epk2 (window-local writes -> L2-coalesced). Emits offsets.
__global__ __launch_bounds__(512) void bucket_sort_kernel(
    const int* __restrict__ gcur, const uint2* __restrict__ epk,
    uint2* __restrict__ epk2, int* __restrict__ offsets2)
{
    __shared__ int bh[128];
    __shared__ int sc[128];

    int b = blockIdx.x, t = threadIdx.x;
    int base  = b * BCAP;
    int total = gcur[b] - base;
    if (total > BCAP) total = BCAP;

    if (t < 128) bh[t] = 0;
    __syncthreads();
    for (int i = t; i < total; i += 512)
        atomicAdd(&bh[(epk[base + i].y >> 15) & 127], 1);
    __syncthreads();

    int v = 0;
    if (t < 128) { v = bh[t]; sc[t] = v; }
    __syncthreads();
    for (int off = 1; off < 128; off <<= 1) {
        int x = 0;
        if (t < 128 && t >= off) x = sc[t - off];
        __syncthreads();
        if (t < 128 && t >= off) sc[t] += x;
        __syncthreads();
    }
    if (t < 128) {
        int ex = sc[t] - v;
        offsets2[b * 129 + t] = ex;
        if (t == 127) offsets2[b * 129 + 128] = sc[127];
        bh[t] = ex;                 // running cursor
    }
    __syncthreads();

    for (int i = t; i < total; i += 512) {
        uint2 r = epk[base + i];
        int pos = atomicAdd(&bh[(r.y >> 15) & 127], 1);
        epk2[base + pos] = r;
    }
}

// One wave per node (100K waves). 8 lanes per edge, dwordx4 gathers:
// 8 edges in flight per wave iteration, 2-way unrolled (16 edges / 2 loads
// outstanding). Lane = g*8 + sl: reads words 4sl..4sl+3 of record (k+g)'s
// src row -> dims {4sl..4sl+3} (x half) and {4sl+32..4sl+35} (y half).
// Final 3-step shfl_xor tree over the 8 record-groups, float4 stores.
__global__ __launch_bounds__(256) void accumulate_kernel(
    const unsigned int* __restrict__ xbf,
    const int* __restrict__ offsets2, const uint2* __restrict__ epk2,
    float* __restrict__ A1, float* __restrict__ cnt, int Ntot)
{
    int idx  = blockIdx.x * 256 + threadIdx.x;
    int n    = idx >> 6;
    int lane = idx & 63;
    if (n >= Ntot) return;
    int sl  = lane & 7;       // word-group within row
    int g   = lane >> 3;      // record-group 0..7
    int b   = n >> 7;
    int loc = n & 127;

    int s0 = b * BCAP + offsets2[b * 129 + loc];
    int s1 = b * BCAP + offsets2[b * 129 + loc + 1];

    float ax0 = 0.f, ax1 = 0.f, ax2 = 0.f, ax3 = 0.f;
    float ay0 = 0.f, ay1 = 0.f, ay2 = 0.f, ay3 = 0.f;
    float c = 0.f;

    for (int base = s0; base < s1; base += 64) {
        int m = s1 - base; if (m > 64) m = 64;
        unsigned int px = 0u, py = 0u;            // 0 => w=0 (src 0 harmless)
        if (lane < m) { uint2 pk = epk2[base + lane]; px = pk.x; py = pk.y; }
        for (int k = 0; k < m; k += 16) {
            // two independent record-groups; both gathers issued before FMAs
            unsigned int sx0 = __shfl(px, k + g);
            unsigned int sy0 = __shfl(py, k + g);
            unsigned int sx1 = __shfl(px, k + 8 + g);
            unsigned int sy1 = __shfl(py, k + 8 + g);
            uint4 u0 = *(const uint4*)(xbf + (size_t)sx0 * 32 + 4 * sl);
            uint4 u1 = *(const uint4*)(xbf + (size_t)sx1 * 32 + 4 * sl);
            float w0 = (float)(sy0 & 0x7fffu) * (1.f / 32767.f);
            float w1 = (float)(sy1 & 0x7fffu) * (1.f / 32767.f);
            ax0 = fmaf(w0, __uint_as_float(u0.x << 16), ax0);
            ax1 = fmaf(w0, __uint_as_float(u0.y << 16), ax1);
            ax2 = fmaf(w0, __uint_as_float(u0.z << 16), ax2);
            ax3 = fmaf(w0, __uint_as_float(u0.w << 16), ax3);
            ay0 = fmaf(w0, __uint_as_float(u0.x & 0xffff0000u), ay0);
            ay1 = fmaf(w0, __uint_as_float(u0.y & 0xffff0000u), ay1);
            ay2 = fmaf(w0, __uint_as_float(u0.z & 0xffff0000u), ay2);
            ay3 = fmaf(w0, __uint_as_float(u0.w & 0xffff0000u), ay3);
            c += w0;
            ax0 = fmaf(w1, __uint_as_float(u1.x << 16), ax0);
            ax1 = fmaf(w1, __uint_as_float(u1.y << 16), ax1);
            ax2 = fmaf(w1, __uint_as_float(u1.z << 16), ax2);
            ax3 = fmaf(w1, __uint_as_float(u1.w << 16), ax3);
            ay0 = fmaf(w1, __uint_as_float(u1.x & 0xffff0000u), ay0);
            ay1 = fmaf(w1, __uint_as_float(u1.y & 0xffff0000u), ay1);
            ay2 = fmaf(w1, __uint_as_float(u1.z & 0xffff0000u), ay2);
            ay3 = fmaf(w1, __uint_as_float(u1.w & 0xffff0000u), ay3);
            c += w1;
        }
    }

    // reduce across the 8 record-groups (lane bits 3,4,5)
    #pragma unroll
    for (int off = 8; off < 64; off <<= 1) {
        ax0 += __shfl_xor(ax0, off); ax1 += __shfl_xor(ax1, off);
        ax2 += __shfl_xor(ax2, off); ax3 += __shfl_xor(ax3, off);
        ay0 += __shfl_xor(ay0, off); ay1 += __shfl_xor(ay1, off);
        ay2 += __shfl_xor(ay2, off); ay3 += __shfl_xor(ay3, off);
        c   += __shfl_xor(c,   off);
    }

    if (g == 0) {
        float4 vx; vx.x = ax0; vx.y = ax1; vx.z = ax2; vx.w = ax3;
        float4 vy; vy.x = ay0; vy.y = ay1; vy.z = ay2; vy.w = ay3;
        *(float4*)(A1 + (size_t)n * 64 + 4 * sl)      = vx;
        *(float4*)(A1 + (size_t)n * 64 + 32 + 4 * sl) = vy;
        if (sl == 0) cnt[n] = c;
    }
}

// 32 rows/block. acc += a1*(w1 + xd*w2); stride-65 LDS transpose.
// xd unpack matches the (f, f+32) word packing of xbf.
__global__ __launch_bounds__(256) void node_gemm_kernel(
    const float* __restrict__ A1, const float* __restrict__ cnt,
    const unsigned int* __restrict__ xbf,
    const float* __restrict__ W1, const float* __restrict__ b1,
    const float* __restrict__ W2, const float* __restrict__ b2,
    float* __restrict__ out, int Ntot)
{
    __shared__ float  w1t[64 * 65];
    __shared__ float  w2t[64 * 65];
    __shared__ float4 sA1v[32][16];
    __shared__ float4 sXdv[32][16];
    __shared__ float  scn[32];

    int t = threadIdx.x;
    for (int i = t; i < 64 * 64; i += 256) {
        int o = i >> 6, d = i & 63;
        w1t[d * 65 + o] = W1[i];
        w2t[d * 65 + o] = W2[i];
    }
    int base = blockIdx.x * 32;
    const float4* A1v = (const float4*)A1;
    for (int i = t; i < 32 * 16; i += 256) {
        int r = i >> 4, q = i & 15;
        int row = base + r;
        float4 zz; zz.x = zz.y = zz.z = zz.w = 0.f;
        if (row < Ntot) {
            sA1v[r][q] = A1v[(size_t)row * 16 + q];
            int wb = (q & 7) * 4;
            unsigned int u0 = xbf[row * 32 + wb + 0];
            unsigned int u1 = xbf[row * 32 + wb + 1];
            unsigned int u2 = xbf[row * 32 + wb + 2];
            unsigned int u3 = xbf[row * 32 + wb + 3];
            float4 xd;
            if (q < 8) {
                xd.x = __uint_as_float(u0 << 16);
                xd.y = __uint_as_float(u1 << 16);
                xd.z = __uint_as_float(u2 << 16);
                xd.w = __uint_as_float(u3 << 16);
            } else {
                xd.x = __uint_as_float(u0 & 0xffff0000u);
                xd.y = __uint_as_float(u1 & 0xffff0000u);
                xd.z = __uint_as_float(u2 & 0xffff0000u);
                xd.w = __uint_as_float(u3 & 0xffff0000u);
            }
            sXdv[r][q] = xd;
        } else { sA1v[r][q] = zz; sXdv[r][q] = zz; }
    }
    if (t < 32) scn[t] = (base + t < Ntot) ? cnt[base + t] : 0.f;
    __syncthreads();

    int o  = t & 63;
    int r0 = t >> 6;
    float bsum = b1[o] + b2[o];
    float acc[8];
    #pragma unroll
    for (int k = 0; k < 8; ++k) acc[k] = scn[r0 + 4 * k] * bsum;

    for (int q = 0; q < 16; ++q) {
        float w10 = w1t[(4 * q + 0) * 65 + o];
        float w11 = w1t[(4 * q + 1) * 65 + o];
        float w12 = w1t[(4 * q + 2) * 65 + o];
        float w13 = w1t[(4 * q + 3) * 65 + o];
        float w20 = w2t[(4 * q + 0) * 65 + o];
        float w21 = w2t[(4 * q + 1) * 65 + o];
        float w22 = w2t[(4 * q + 2) * 65 + o];
        float w23 = w2t[(4 * q + 3) * 65 + o];
        #pragma unroll
        for (int k = 0; k < 8; ++k) {
            float4 a1 = sA1v[r0 + 4 * k][q];
            float4 xd = sXdv[r0 + 4 * k][q];
            acc[k] += a1.x * fmaf(xd.x, w20, w10)
                    + a1.y * fmaf(xd.y, w21, w11)
                    + a1.z * fmaf(xd.z, w22, w12)
                    + a1.w * fmaf(xd.w, w23, w13);
        }
    }

    #pragma unroll
    for (int k = 0; k < 8; ++k) {
        int row = base + r0 + 4 * k;
        if (row < Ntot) {
            float a = acc[k];
            out[(size_t)row * 64 + o] = (a > 0.f) ? a : 0.2f * a;
        }
    }
}

extern "C" void kernel_launch(void* const* d_in, const int* in_sizes, int n_in,
                              void* d_out, int out_size, void* d_ws, size_t ws_size,
                              hipStream_t stream) {
    const float* srcEmb = (const float*)d_in[0];
    const float* dstEmb = (const float*)d_in[1];
    const float* norm   = (const float*)d_in[2];
    const float* W1     = (const float*)d_in[3];
    const float* b1     = (const float*)d_in[4];
    const float* W2     = (const float*)d_in[5];
    const float* b2     = (const float*)d_in[6];
    const int*   es     = (const int*)d_in[7];
    const int*   ed     = (const int*)d_in[8];

    const int n_src = in_sizes[0] / 64;
    const int n_dst = in_sizes[1] / 64;
    const int Ntot  = n_src + n_dst;
    const int E     = in_sizes[7];
    const int NB    = (Ntot + 127) >> 7;     // 128-node buckets (NB <= 1024)

    // Workspace carve-up (4-byte units); epk/xbf 16B-aligned (dwordx4 gathers).
    float* cnt      = (float*)d_ws;                          // Ntot
    int*   gcur     = (int*)(cnt + Ntot);                    // NB
    int*   offsets2 = gcur + NB;                             // NB*129
    size_t off4     = (size_t)Ntot + NB + (size_t)NB * 129;
    off4 = (off4 + 3) & ~(size_t)3;
    uint2* epk      = (uint2*)((float*)d_ws + off4);         // NB*BCAP uint2
    uint2* epk2     = epk + (size_t)NB * BCAP;               // NB*BCAP uint2
    unsigned int* xbf = (unsigned int*)(epk2 + (size_t)NB * BCAP); // Ntot*32
    float* A1       = (float*)d_out;                         // Ntot*64

    prep_init_kernel<<<(Ntot * 32 + 255) / 256, 256, 0, stream>>>(
        srcEmb, dstEmb, xbf, gcur, Ntot, n_src, NB);

    part_scatter_kernel<<<(E + CHUNK - 1) / CHUNK, 1024, 0, stream>>>(
        es, ed, norm, gcur, epk, E, NB);

    bucket_sort_kernel<<<NB, 512, 0, stream>>>(gcur, epk, epk2, offsets2);

    accumulate_kernel<<<(Ntot + 3) / 4, 256, 0, stream>>>(
        xbf, offsets2, epk2, A1, cnt, Ntot);

    node_gemm_kernel<<<(Ntot + 31) / 32, 256, 0, stream>>>(
        A1, cnt, xbf, W1, b1, W2, b2, (float*)d_out, Ntot);
}

// Round 3
// 198.535 us; speedup vs baseline: 1.2549x; 1.1545x over previous
//
#include <hip/hip_runtime.h>
#include <hip/hip_bf16.h>

// GCN layer. Algebra: A2[n] = A1[n].*x[n], so only A1 (+cnt) is edge-accumulated.
//   out[n] = LeakyReLU(A1@W1^T + (A1.*x[n])@W2^T + c*(b1+b2), 0.2)
//
// Pipeline (5 kernels):
//   1. prep_init: bf16 node table + gcur[b] = b*BCAP (region bases)
//   2. part_scatter (1024 thr, 4096 edges/block): LDS bin-sort by bucket
//      (dst>>7, NB=782 bins), ONE global atomicAdd per non-empty bucket
//      reserves a CONTIGUOUS run, runs dumped coalesced.
//   3. bucket_sort (782 blocks x 512 thr): per 128-node bucket, hist loc,
//      scan, direct global scatter into epk2. Emits offsets2[b*129+loc].
//   4. accumulate: ONE WAVE PER NODE. 8 lanes x dwordx4 per edge, 2-way
//      unrolled (R9). R10: emits Acat = [a1 | a1.*xd] as packed bf16
//      (256 B/row, same traffic as old fp32 A1) straight into d_out.
//   5. node_gemm (R10): MFMA 16x16x32 bf16. out = Acat @ Wcat^T, M=100K
//      K=128 N=64. 64 rows/block, 4 waves, W in 17 KB LDS (k-order matches
//      accumulate's natural lane packing -- k is a free permutation applied
//      to BOTH operands). R9's VALU gemm was LDS+VALU co-bound at 55 us;
//      MFMA compute is ~0.2 us, kernel is pure streaming (~51 MB).
//   R11 == R10 resubmit: R10 bench died with "container failed twice"
//   (infra flake, no kernel verdict). Audit found no fault path: in-place
//   Acat/out is block-local, LDS stride 68 words = 17x16B stays aligned,
//   k-perm verified on both halves.
//
// Record: uint2{ src, (dst<<15) | q15(norm) }  (dst<131072 fits 17 bits)
// ws (4B units): cnt[N] | gcur[NB] | offsets2[NB*129] | epk[NB*BCAP*2] |
//                epk2[NB*BCAP*2] | xbf[N*32]   (epk 16B-aligned for dwordx4)
// xbf packing: word w of node n = bf16(x[w+32])<<16 | bf16(x[w])
// Acat packing (64 u32 words/row, k-permuted): lane sl (0..7) owns
//   words 4sl..4sl+3   = pk(a1[4sl],a1[4sl+1]) pk(a1[4sl+2],a1[4sl+3])
//                        pk(a1[4sl+32],..33)   pk(a1[4sl+34],..35)
//   words 32+4sl..+3   = same with a2 = a1.*xd
// Wcat LDS mirrors this k-order; word j<32 from W1, j>=32 from W2.

#define CHUNK 4096
#define NBMAX 1024
#define BCAP  2304   // per-128-node-bucket capacity: mean 2046, sigma 45 -> +5.7σ

typedef __attribute__((ext_vector_type(8))) short short8v;   // 8 bf16
typedef __attribute__((ext_vector_type(4))) float f32x4;
union U4S8 { uint4 u; short8v s; };

__device__ __forceinline__ unsigned int f2bf(float f) {
    unsigned int u = __float_as_uint(f);
    u += 0x7fffu + ((u >> 16) & 1u);
    return u >> 16;
}
__device__ __forceinline__ unsigned int pkbf(float lo, float hi) {
    return (f2bf(hi) << 16) | f2bf(lo);
}

__global__ __launch_bounds__(256) void prep_init_kernel(
    const float* __restrict__ srcEmb, const float* __restrict__ dstEmb,
    unsigned int* __restrict__ xbf, int* __restrict__ gcur,
    int Ntot, int n_src, int NB)
{
    int i = blockIdx.x * 256 + threadIdx.x;
    if (i < NB) gcur[i] = i * BCAP;
    if (i >= Ntot * 32) return;
    int n = i >> 5, w = i & 31;
    const float* row = (n < n_src) ? srcEmb + (size_t)n * 64
                                   : dstEmb + (size_t)(n - n_src) * 64;
    xbf[i] = (f2bf(row[w + 32]) << 16) | f2bf(row[w]);
}

// 1024 threads, 4096 edges/block (4 per thread, held in registers).
__global__ __launch_bounds__(1024) void part_scatter_kernel(
    const int* __restrict__ es, const int* __restrict__ ed,
    const float* __restrict__ norm, int* __restrict__ gcur,
    uint2* __restrict__ epk, int E, int NB)
{
    __shared__ int   bcnt[NBMAX];    // counts -> local cursors
    __shared__ int   lstart[NBMAX];  // local run starts
    __shared__ int   gbase[NBMAX];   // reserved global run bases
    __shared__ int   sc[NBMAX];
    __shared__ uint2 sorted[CHUNK];  // 32 KB

    int t  = threadIdx.x;
    int e0 = blockIdx.x * CHUNK;

    bcnt[t] = 0;
    __syncthreads();

    // pass 1: histogram by bucket; dst held in registers for pass 2
    int dreg[4];
    #pragma unroll
    for (int k = 0; k < 4; ++k) {
        int e = e0 + t + k * 1024;
        dreg[k] = (e < E) ? ed[e] : -1;
        if (dreg[k] >= 0) atomicAdd(&bcnt[dreg[k] >> 7], 1);
    }
    __syncthreads();

    // full-block scan over NBMAX bins (one bin per thread) + run reservation
    int c = (t < NB) ? bcnt[t] : 0;
    sc[t] = c;
    __syncthreads();
    for (int off = 1; off < NBMAX; off <<= 1) {
        int x = 0;
        if (t >= off) x = sc[t - off];
        __syncthreads();
        if (t >= off) sc[t] += x;
        __syncthreads();
    }
    int ex = sc[t] - c;
    lstart[t] = ex;
    bcnt[t]   = ex;                 // becomes local cursor
    if (c > 0) gbase[t] = atomicAdd(&gcur[t], c);
    __syncthreads();

    // pass 2: place records into LDS sorted-by-bucket order
    #pragma unroll
    for (int k = 0; k < 4; ++k) {
        int e = e0 + t + k * 1024;
        if (dreg[k] >= 0) {
            unsigned int q = (unsigned int)(norm[e] * 32767.f + 0.5f);
            if (q > 32767u) q = 32767u;
            int lp = atomicAdd(&bcnt[dreg[k] >> 7], 1);
            uint2 r; r.x = (unsigned int)es[e];
            r.y = ((unsigned int)dreg[k] << 15) | q;
            sorted[lp] = r;
        }
    }
    __syncthreads();

    // pass 3: coalesced run dump
    int total = E - e0; if (total > CHUNK) total = CHUNK;
    for (int i = t; i < total; i += 1024) {
        uint2 r = sorted[i];
        int b = (int)(r.y >> 22);                 // dst >> 7
        int gpos = gbase[b] + (i - lstart[b]);
        if (gpos < (b + 1) * BCAP)                // overflow guard
            epk[gpos] = r;
    }
}

// One 512-thread block per 128-node bucket: hist by loc, scan, direct global
// scatter into epk2 (window-local writes -> L2-coalesced). Emits offsets.
__global__ __launch_bounds__(512) void bucket_sort_kernel(
    const int* __restrict__ gcur, const uint2* __restrict__ epk,
    uint2* __restrict__ epk2, int* __restrict__ offsets2)
{
    __shared__ int bh[128];
    __shared__ int sc[128];

    int b = blockIdx.x, t = threadIdx.x;
    int base  = b * BCAP;
    int total = gcur[b] - base;
    if (total > BCAP) total = BCAP;

    if (t < 128) bh[t] = 0;
    __syncthreads();
    for (int i = t; i < total; i += 512)
        atomicAdd(&bh[(epk[base + i].y >> 15) & 127], 1);
    __syncthreads();

    int v = 0;
    if (t < 128) { v = bh[t]; sc[t] = v; }
    __syncthreads();
    for (int off = 1; off < 128; off <<= 1) {
        int x = 0;
        if (t < 128 && t >= off) x = sc[t - off];
        __syncthreads();
        if (t < 128 && t >= off) sc[t] += x;
        __syncthreads();
    }
    if (t < 128) {
        int ex = sc[t] - v;
        offsets2[b * 129 + t] = ex;
        if (t == 127) offsets2[b * 129 + 128] = sc[127];
        bh[t] = ex;                 // running cursor
    }
    __syncthreads();

    for (int i = t; i < total; i += 512) {
        uint2 r = epk[base + i];
        int pos = atomicAdd(&bh[(r.y >> 15) & 127], 1);
        epk2[base + pos] = r;
    }
}

// One wave per node (100K waves). 8 lanes per edge, dwordx4 gathers:
// 8 edges in flight per wave iteration, 2-way unrolled. Final 3-step
// shfl_xor tree, then emit Acat = [a1 | a1.*xd] packed bf16 (2 uint4/lane).
__global__ __launch_bounds__(256) void accumulate_kernel(
    const unsigned int* __restrict__ xbf,
    const int* __restrict__ offsets2, const uint2* __restrict__ epk2,
    unsigned int* __restrict__ Acat, float* __restrict__ cnt, int Ntot)
{
    int idx  = blockIdx.x * 256 + threadIdx.x;
    int n    = idx >> 6;
    int lane = idx & 63;
    if (n >= Ntot) return;
    int sl  = lane & 7;       // word-group within row
    int g   = lane >> 3;      // record-group 0..7
    int b   = n >> 7;
    int loc = n & 127;

    int s0 = b * BCAP + offsets2[b * 129 + loc];
    int s1 = b * BCAP + offsets2[b * 129 + loc + 1];

    float ax0 = 0.f, ax1 = 0.f, ax2 = 0.f, ax3 = 0.f;
    float ay0 = 0.f, ay1 = 0.f, ay2 = 0.f, ay3 = 0.f;
    float c = 0.f;

    for (int base = s0; base < s1; base += 64) {
        int m = s1 - base; if (m > 64) m = 64;
        unsigned int px = 0u, py = 0u;            // 0 => w=0 (src 0 harmless)
        if (lane < m) { uint2 pk = epk2[base + lane]; px = pk.x; py = pk.y; }
        for (int k = 0; k < m; k += 16) {
            // two independent record-groups; both gathers issued before FMAs
            unsigned int sx0 = __shfl(px, k + g);
            unsigned int sy0 = __shfl(py, k + g);
            unsigned int sx1 = __shfl(px, k + 8 + g);
            unsigned int sy1 = __shfl(py, k + 8 + g);
            uint4 u0 = *(const uint4*)(xbf + (size_t)sx0 * 32 + 4 * sl);
            uint4 u1 = *(const uint4*)(xbf + (size_t)sx1 * 32 + 4 * sl);
            float w0 = (float)(sy0 & 0x7fffu) * (1.f / 32767.f);
            float w1 = (float)(sy1 & 0x7fffu) * (1.f / 32767.f);
            ax0 = fmaf(w0, __uint_as_float(u0.x << 16), ax0);
            ax1 = fmaf(w0, __uint_as_float(u0.y << 16), ax1);
            ax2 = fmaf(w0, __uint_as_float(u0.z << 16), ax2);
            ax3 = fmaf(w0, __uint_as_float(u0.w << 16), ax3);
            ay0 = fmaf(w0, __uint_as_float(u0.x & 0xffff0000u), ay0);
            ay1 = fmaf(w0, __uint_as_float(u0.y & 0xffff0000u), ay1);
            ay2 = fmaf(w0, __uint_as_float(u0.z & 0xffff0000u), ay2);
            ay3 = fmaf(w0, __uint_as_float(u0.w & 0xffff0000u), ay3);
            c += w0;
            ax0 = fmaf(w1, __uint_as_float(u1.x << 16), ax0);
            ax1 = fmaf(w1, __uint_as_float(u1.y << 16), ax1);
            ax2 = fmaf(w1, __uint_as_float(u1.z << 16), ax2);
            ax3 = fmaf(w1, __uint_as_float(u1.w << 16), ax3);
            ay0 = fmaf(w1, __uint_as_float(u1.x & 0xffff0000u), ay0);
            ay1 = fmaf(w1, __uint_as_float(u1.y & 0xffff0000u), ay1);
            ay2 = fmaf(w1, __uint_as_float(u1.z & 0xffff0000u), ay2);
            ay3 = fmaf(w1, __uint_as_float(u1.w & 0xffff0000u), ay3);
            c += w1;
        }
    }

    // reduce across the 8 record-groups (lane bits 3,4,5)
    #pragma unroll
    for (int off = 8; off < 64; off <<= 1) {
        ax0 += __shfl_xor(ax0, off); ax1 += __shfl_xor(ax1, off);
        ax2 += __shfl_xor(ax2, off); ax3 += __shfl_xor(ax3, off);
        ay0 += __shfl_xor(ay0, off); ay1 += __shfl_xor(ay1, off);
        ay2 += __shfl_xor(ay2, off); ay3 += __shfl_xor(ay3, off);
        c   += __shfl_xor(c,   off);
    }

    if (g == 0) {
        // xd for this node's own dims: word 4sl+i holds (x[4sl+i], x[4sl+i+32])
        uint4 xv = *(const uint4*)(xbf + (size_t)n * 32 + 4 * sl);
        float xl0 = __uint_as_float(xv.x << 16);
        float xl1 = __uint_as_float(xv.y << 16);
        float xl2 = __uint_as_float(xv.z << 16);
        float xl3 = __uint_as_float(xv.w << 16);
        float xh0 = __uint_as_float(xv.x & 0xffff0000u);
        float xh1 = __uint_as_float(xv.y & 0xffff0000u);
        float xh2 = __uint_as_float(xv.z & 0xffff0000u);
        float xh3 = __uint_as_float(xv.w & 0xffff0000u);

        uint4 w0;
        w0.x = pkbf(ax0, ax1);
        w0.y = pkbf(ax2, ax3);
        w0.z = pkbf(ay0, ay1);
        w0.w = pkbf(ay2, ay3);
        uint4 w1;
        w1.x = pkbf(ax0 * xl0, ax1 * xl1);
        w1.y = pkbf(ax2 * xl2, ax3 * xl3);
        w1.z = pkbf(ay0 * xh0, ay1 * xh1);
        w1.w = pkbf(ay2 * xh2, ay3 * xh3);
        *(uint4*)(Acat + (size_t)n * 64 + 4 * sl)      = w0;
        *(uint4*)(Acat + (size_t)n * 64 + 32 + 4 * sl) = w1;
        if (sl == 0) cnt[n] = c;
    }
}

// MFMA gemm: 64 rows/block (4 waves x 16), out = Acat @ Wcat^T + cnt*(b1+b2),
// LeakyReLU. Wcat LDS built with the same k-permutation as Acat packing.
// In-place over d_out: each wave reads only its own 16 rows before writing.
__global__ __launch_bounds__(256) void node_gemm_kernel(
    const unsigned int* __restrict__ Acat, const float* __restrict__ cnt,
    const float* __restrict__ W1, const float* __restrict__ b1,
    const float* __restrict__ W2, const float* __restrict__ b2,
    float* __restrict__ out, int Ntot)
{
    __shared__ unsigned int wlds[64 * 68];   // [o][68 words], 272B row = 17x16B

    int t     = threadIdx.x;
    int lane  = t & 63;
    int wv    = t >> 6;
    int base  = blockIdx.x * 64;
    int row16 = lane & 15;    // A-row within 16-tile / D-col within 16-tile
    int q     = lane >> 4;    // k-block 0..3

    // A-frags: 4 x 16B global loads per lane (clamped rows; guarded on store)
    int arow = base + wv * 16 + row16;
    if (arow >= Ntot) arow = Ntot - 1;
    const uint4* ap = (const uint4*)(Acat + (size_t)arow * 64);
    uint4 af[4];
    #pragma unroll
    for (int s = 0; s < 4; ++s) af[s] = ap[s * 4 + q];

    // Build Wcat LDS (bf16-pair words, k-order mirrors Acat lane packing)
    for (int i = t; i < 64 * 64; i += 256) {
        int o = i >> 6, j = i & 63;
        int jj = j & 31, sl = jj >> 2, tt = jj & 3;
        int d0 = 4 * sl + ((tt & 1) << 1) + ((tt & 2) ? 32 : 0);
        const float* wsrc = (j < 32) ? W1 : W2;
        wlds[o * 68 + j] = pkbf(wsrc[o * 64 + d0], wsrc[o * 64 + d0 + 1]);
    }

    // acc init: cnt[row]*(b1[col]+b2[col]) (fp32-exact bias path)
    float cload[4];
    #pragma unroll
    for (int r = 0; r < 4; ++r) {
        int grow = base + wv * 16 + q * 4 + r;
        cload[r] = cnt[grow < Ntot ? grow : (Ntot - 1)];
    }
    f32x4 acc[4];
    #pragma unroll
    for (int j = 0; j < 4; ++j) {
        int col = j * 16 + row16;
        float bs = b1[col] + b2[col];
        #pragma unroll
        for (int r = 0; r < 4; ++r) acc[j][r] = cload[r] * bs;
    }
    __syncthreads();

    #pragma unroll
    for (int s = 0; s < 4; ++s) {
        U4S8 a; a.u = af[s];
        #pragma unroll
        for (int j = 0; j < 4; ++j) {
            int o = j * 16 + row16;
            U4S8 bb; bb.u = *(const uint4*)(wlds + o * 68 + s * 16 + q * 4);
            acc[j] = __builtin_amdgcn_mfma_f32_16x16x32_bf16(
                a.s, bb.s, acc[j], 0, 0, 0);
        }
    }

    // epilogue: D row=(lane>>4)*4+r, col=j*16+(lane&15)
    #pragma unroll
    for (int r = 0; r < 4; ++r) {
        int grow = base + wv * 16 + q * 4 + r;
        if (grow < Ntot) {
            #pragma unroll
            for (int j = 0; j < 4; ++j) {
                float a = acc[j][r];
                out[(size_t)grow * 64 + j * 16 + row16] = (a > 0.f) ? a : 0.2f * a;
            }
        }
    }
}

extern "C" void kernel_launch(void* const* d_in, const int* in_sizes, int n_in,
                              void* d_out, int out_size, void* d_ws, size_t ws_size,
                              hipStream_t stream) {
    const float* srcEmb = (const float*)d_in[0];
    const float* dstEmb = (const float*)d_in[1];
    const float* norm   = (const float*)d_in[2];
    const float* W1     = (const float*)d_in[3];
    const float* b1     = (const float*)d_in[4];
    const float* W2     = (const float*)d_in[5];
    const float* b2     = (const float*)d_in[6];
    const int*   es     = (const int*)d_in[7];
    const int*   ed     = (const int*)d_in[8];

    const int n_src = in_sizes[0] / 64;
    const int n_dst = in_sizes[1] / 64;
    const int Ntot  = n_src + n_dst;
    const int E     = in_sizes[7];
    const int NB    = (Ntot + 127) >> 7;     // 128-node buckets (NB <= 1024)

    // Workspace carve-up (4-byte units); epk/xbf 16B-aligned (dwordx4 gathers).
    float* cnt      = (float*)d_ws;                          // Ntot
    int*   gcur     = (int*)(cnt + Ntot);                    // NB
    int*   offsets2 = gcur + NB;                             // NB*129
    size_t off4     = (size_t)Ntot + NB + (size_t)NB * 129;
    off4 = (off4 + 3) & ~(size_t)3;
    uint2* epk      = (uint2*)((float*)d_ws + off4);         // NB*BCAP uint2
    uint2* epk2     = epk + (size_t)NB * BCAP;               // NB*BCAP uint2
    unsigned int* xbf = (unsigned int*)(epk2 + (size_t)NB * BCAP); // Ntot*32
    unsigned int* Acat = (unsigned int*)d_out;               // Ntot*64 words (bf16 x128)

    prep_init_kernel<<<(Ntot * 32 + 255) / 256, 256, 0, stream>>>(
        srcEmb, dstEmb, xbf, gcur, Ntot, n_src, NB);

    part_scatter_kernel<<<(E + CHUNK - 1) / CHUNK, 1024, 0, stream>>>(
        es, ed, norm, gcur, epk, E, NB);

    bucket_sort_kernel<<<NB, 512, 0, stream>>>(gcur, epk, epk2, offsets2);

    accumulate_kernel<<<(Ntot + 3) / 4, 256, 0, stream>>>(
        xbf, offsets2, epk2, Acat, cnt, Ntot);

    node_gemm_kernel<<<(Ntot + 63) / 64, 256, 0, stream>>>(
        Acat, cnt, W1, b1, W2, b2, (float*)d_out, Ntot);
}